// Round 4
// baseline (1045.625 us; speedup 1.0000x reference)
//
#include <hip/hip_runtime.h>
#include <cfloat>
#include <cstddef>

// ---------------------------------------------------------------------------
// SemanticRQVAE forward, round 3: register-only MFMA K-loops (no LDS staging,
// no K-loop barriers). Operands stream from L2-resident tile-ready split
// buffers; A converts f32 -> f16 hi/lo in-register.
// d_out layout (floats): recon (25165824) | indices as float (262144)
//                        | recon_loss | commit_loss
// ---------------------------------------------------------------------------

#define BATCH   65536
#define EDIM    384
#define HDIM    512
#define NCODE   256
#define NQ      4

#define OUT_IDX_OFF 25165824          // BATCH*EDIM
#define OUT_RL_OFF  25427968          // + BATCH*4
#define WS_BUFA     0
#define WS_BUFB     33554432
#define WS_CBSPL    67108864
#define WS_CNORM    67633152
#define WS_COMMITP  67634176
#define WS_RECONP   67636224
#define WS_W1S      67637760          // 384*512 floats
#define WS_W2S      67834368          // 512*512
#define WS_W3S      68096512          // 512*512
#define WS_W4S      68358656          // 512*384  (ends 68555264)

typedef _Float16 half8 __attribute__((ext_vector_type(8)));
typedef float    f32x16 __attribute__((ext_vector_type(16)));

__device__ __forceinline__ void cvt_hl(const float4& a0, const float4& a1,
                                       half8& h, half8& l)
{
    float vs[8] = {a0.x, a0.y, a0.z, a0.w, a1.x, a1.y, a1.z, a1.w};
#pragma unroll
    for (int j = 0; j < 8; ++j) {
        _Float16 hv = (_Float16)vs[j];
        h[j] = hv;
        l[j] = (_Float16)(vs[j] - (float)hv);
    }
}

// ---------------------------------------------------------------------------
// Split f32 weight W[K][N] into f16 hi/lo, tile-ready u16 layout:
//   entry(kt, hl, khalf, col) = ((kt*2 + hl)*2 + khalf)*N + col, 8 u16 each
//   holding k = kt*16 + khalf*8 + j.
// ---------------------------------------------------------------------------
__global__ __launch_bounds__(256)
void split_w(const float* __restrict__ W, unsigned short* __restrict__ out,
             int N, int K)
{
    int u = blockIdx.x * 256 + threadIdx.x;
    int col  = u % N;
    int rem  = u / N;
    int khalf = rem & 1;
    int kt    = rem >> 1;
    int kbase = kt * 16 + khalf * 8;
    half8 h, l;
#pragma unroll
    for (int j = 0; j < 8; ++j) {
        float v = W[(size_t)(kbase + j) * N + col];
        _Float16 hv = (_Float16)v;
        h[j] = hv;
        l[j] = (_Float16)(v - (float)hv);
    }
    size_t eh = ((size_t)(kt * 4 + khalf)) * N + col;        // hl=0
    size_t el = ((size_t)(kt * 4 + 2 + khalf)) * N + col;    // hl=1
    *reinterpret_cast<half8*>(out + eh * 8) = h;
    *reinterpret_cast<half8*>(out + el * 8) = l;
}

// ---------------------------------------------------------------------------
// Register-only MFMA GEMM: C[M,N] = act(A[M,K] @ W[K,N] + bias).
// Block: 128 rows x BN cols, 4 waves. BN=256 -> waves 2x2 (64 rows x 128 cols
// each); BN=128 -> waves 4x1 (32 x 128). No LDS in the K-loop; B-fragments
// are 16B-coalesced global loads from the split layout, A-fragments are
// 2x16B row loads converted to f16 h/l in-register. 3 MFMA per frag per kt.
// ---------------------------------------------------------------------------
template <int BN, bool RELU, bool LOSS>
__global__ __launch_bounds__(256, 2)
void gemm_reg(const float* __restrict__ A, const unsigned short* __restrict__ Wsp,
              const float* __restrict__ bias, float* __restrict__ C,
              const float* __restrict__ X, float* __restrict__ lossP,
              int N, int K)
{
    constexpr int WN = BN / 128;          // waves along N
    constexpr int WM = 4 / WN;            // waves along M
    constexpr int MR = 128 / WM;          // rows per wave
    constexpr int FM = MR / 32;           // 32-row frags per wave

    const int tid  = threadIdx.x;
    const int wid  = tid >> 6;
    const int lane = tid & 63;
    const int l31  = lane & 31;
    const int lh   = lane >> 5;
    const int wm   = wid / WN;
    const int wn   = wid % WN;
    const int row0 = blockIdx.y * 128;
    const int n0   = blockIdx.x * BN;
    const int nkt  = K / 16;

    f32x16 acc[FM][4];
#pragma unroll
    for (int m = 0; m < FM; ++m)
#pragma unroll
        for (int n = 0; n < 4; ++n) acc[m][n] = (f32x16)(0.0f);

    const float* ap[FM];
#pragma unroll
    for (int fm = 0; fm < FM; ++fm)
        ap[fm] = A + (size_t)(row0 + wm * MR + fm * 32 + l31) * K + lh * 8;

    const half8* b8 = reinterpret_cast<const half8*>(Wsp);
    const int colb = n0 + wn * 128 + l31;

#pragma unroll 2
    for (int kt = 0; kt < nkt; ++kt) {
        half8 Ah[FM], Al[FM];
#pragma unroll
        for (int fm = 0; fm < FM; ++fm) {
            float4 a0 = *reinterpret_cast<const float4*>(ap[fm] + kt * 16);
            float4 a1 = *reinterpret_cast<const float4*>(ap[fm] + kt * 16 + 4);
            cvt_hl(a0, a1, Ah[fm], Al[fm]);
        }
        const size_t eh = (size_t)(kt * 4 + lh) * N + colb;
        const size_t el = (size_t)(kt * 4 + 2 + lh) * N + colb;
#pragma unroll
        for (int nt = 0; nt < 4; ++nt) {
            half8 Bh = b8[eh + nt * 32];
            half8 Bl = b8[el + nt * 32];
#pragma unroll
            for (int fm = 0; fm < FM; ++fm) {
                acc[fm][nt] = __builtin_amdgcn_mfma_f32_32x32x16_f16(Ah[fm], Bh, acc[fm][nt], 0, 0, 0);
                acc[fm][nt] = __builtin_amdgcn_mfma_f32_32x32x16_f16(Ah[fm], Bl, acc[fm][nt], 0, 0, 0);
                acc[fm][nt] = __builtin_amdgcn_mfma_f32_32x32x16_f16(Al[fm], Bh, acc[fm][nt], 0, 0, 0);
            }
        }
    }

    // epilogue: bias (+relu) (+loss) + stores
    float lacc = 0.f;
#pragma unroll
    for (int fm = 0; fm < FM; ++fm) {
#pragma unroll
        for (int nt = 0; nt < 4; ++nt) {
            const int col = n0 + wn * 128 + nt * 32 + l31;
            const float b = bias[col];
#pragma unroll
            for (int rg = 0; rg < 16; ++rg) {
                const int row = row0 + wm * MR + fm * 32 + (rg & 3) + 8 * (rg >> 2) + 4 * lh;
                float v = acc[fm][nt][rg] + b;
                if (RELU) v = v > 0.f ? v : 0.f;
                C[(size_t)row * N + col] = v;
                if constexpr (LOSS) {
                    float d = v - X[(size_t)row * N + col];
                    lacc = fmaf(d, d, lacc);
                }
            }
        }
    }

    if constexpr (LOSS) {
        __shared__ float red[256];
        red[tid] = lacc;
        __syncthreads();
        for (int s = 128; s > 0; s >>= 1) {
            if (tid < s) red[tid] += red[tid + s];
            __syncthreads();
        }
        if (tid == 0) lossP[blockIdx.y * gridDim.x + blockIdx.x] = red[0];
    }
}

// ---------------------------------------------------------------------------
// codebook squared norms (exact f32)
// ---------------------------------------------------------------------------
__global__ __launch_bounds__(64)
void cnorm_kernel(const float* __restrict__ cb, float* __restrict__ cnorm)
{
    const int code = blockIdx.x;
    const int lane = threadIdx.x;
    const float* r = cb + (size_t)code * HDIM;
    float s = 0.f;
    for (int k = lane; k < HDIM; k += 64) s = fmaf(r[k], r[k], s);
#pragma unroll
    for (int off = 32; off > 0; off >>= 1) s += __shfl_down(s, off);
    if (lane == 0) cnorm[code] = s;
}

// ---------------------------------------------------------------------------
// Split f32 codebook into f16 hi/lo tile-ready layout.
// short8 index: (q*32+kt)*1024 + khalf*256 + code  (h) ; +512 (l)
// ---------------------------------------------------------------------------
__global__ __launch_bounds__(256)
void split_cb(const float* __restrict__ cb, unsigned short* __restrict__ out)
{
    int u = blockIdx.x * 256 + threadIdx.x;
    int q    = u >> 14;
    int rem  = u & 16383;
    int code = rem >> 6;
    int kt   = (rem >> 1) & 31;
    int khalf = rem & 1;
    int k = kt * 16 + khalf * 8;
    const float* p = cb + ((size_t)(q * NCODE + code)) * HDIM + k;
    float4 v0 = *reinterpret_cast<const float4*>(p);
    float4 v1 = *reinterpret_cast<const float4*>(p + 4);
    half8 h, l;
    cvt_hl(v0, v1, h, l);
    size_t o = (size_t)(q * 32 + kt) * 8192 + (size_t)khalf * 2048 + (size_t)code * 8;
    *reinterpret_cast<half8*>(out + o)        = h;
    *reinterpret_cast<half8*>(out + o + 4096) = l;
}

// ---------------------------------------------------------------------------
// One residual-VQ stage, register-only score GEMM (no K-loop LDS/barriers).
// Block: 128 rows x 256 codes, 4 waves 2x2. Argmax / residual-update /
// commit phases unchanged from the correctness-proven round-1 version.
// ---------------------------------------------------------------------------
template <bool LAST>
__global__ __launch_bounds__(256, 2)
void vq_stage(int q,
              const float* __restrict__ Rin, float* __restrict__ Rout,
              const float* __restrict__ zsrc,
              const unsigned short* __restrict__ cbs,
              const float* __restrict__ cb,
              const float* __restrict__ cnorm,
              float* __restrict__ idx_out,
              float* __restrict__ commitP)
{
    __shared__ float sval[2][128];
    __shared__ int   sidx[2][128];
    __shared__ int   idxbuf[128];
    __shared__ float red[256];

    const int tid  = threadIdx.x;
    const int wid  = tid >> 6;
    const int lane = tid & 63;
    const int l31  = lane & 31;
    const int lh   = lane >> 5;
    const int wm   = wid >> 1;
    const int wn   = wid & 1;
    const int row0 = blockIdx.x * 128;

    f32x16 acc[2][4];
#pragma unroll
    for (int m = 0; m < 2; ++m)
#pragma unroll
        for (int n = 0; n < 4; ++n) acc[m][n] = (f32x16)(0.0f);

    const float* ap[2];
#pragma unroll
    for (int fm = 0; fm < 2; ++fm)
        ap[fm] = Rin + (size_t)(row0 + wm * 64 + fm * 32 + l31) * HDIM + lh * 8;

    const half8* c8 = reinterpret_cast<const half8*>(cbs);
    const size_t qbase = (size_t)q * 32 * 1024;
    const int code_b = wn * 128 + l31;

#pragma unroll 4
    for (int kt = 0; kt < 32; ++kt) {
        half8 Ah[2], Al[2];
#pragma unroll
        for (int fm = 0; fm < 2; ++fm) {
            float4 a0 = *reinterpret_cast<const float4*>(ap[fm] + kt * 16);
            float4 a1 = *reinterpret_cast<const float4*>(ap[fm] + kt * 16 + 4);
            cvt_hl(a0, a1, Ah[fm], Al[fm]);
        }
        const size_t eh = qbase + (size_t)kt * 1024 + (size_t)lh * 256 + code_b;
#pragma unroll
        for (int nt = 0; nt < 4; ++nt) {
            half8 Bh = c8[eh + nt * 32];
            half8 Bl = c8[eh + 512 + nt * 32];
#pragma unroll
            for (int fm = 0; fm < 2; ++fm) {
                acc[fm][nt] = __builtin_amdgcn_mfma_f32_32x32x16_f16(Ah[fm], Bh, acc[fm][nt], 0, 0, 0);
                acc[fm][nt] = __builtin_amdgcn_mfma_f32_32x32x16_f16(Ah[fm], Bl, acc[fm][nt], 0, 0, 0);
                acc[fm][nt] = __builtin_amdgcn_mfma_f32_32x32x16_f16(Al[fm], Bh, acc[fm][nt], 0, 0, 0);
            }
        }
    }

    // ---- scores + per-row argmax (first-max tie-break) ----
    const float* cn = cnorm + q * NCODE;
#pragma unroll
    for (int Mt = 0; Mt < 2; ++Mt) {
#pragma unroll
        for (int rg = 0; rg < 16; ++rg) {
            float bv = -FLT_MAX;
            int   bi = 0;
#pragma unroll
            for (int nt = 0; nt < 4; ++nt) {
                const int code = wn * 128 + nt * 32 + l31;
                float s = 2.f * acc[Mt][nt][rg] - cn[code];
                if (s > bv || (s == bv && code < bi)) { bv = s; bi = code; }
            }
#pragma unroll
            for (int m = 1; m < 32; m <<= 1) {
                float ov = __shfl_xor(bv, m, 64);
                int   oi = __shfl_xor(bi, m, 64);
                if (ov > bv || (ov == bv && oi < bi)) { bv = ov; bi = oi; }
            }
            if (l31 == 0) {
                int row = wm * 64 + Mt * 32 + (rg & 3) + 8 * (rg >> 2) + 4 * lh;
                sval[wn][row] = bv;
                sidx[wn][row] = bi;
            }
        }
    }
    __syncthreads();
    if (tid < 128) {
        float v0 = sval[0][tid], v1 = sval[1][tid];
        int   i0 = sidx[0][tid], i1 = sidx[1][tid];
        int b = (v1 > v0 || (v1 == v0 && i1 < i0)) ? i1 : i0;
        idxbuf[tid] = b;
        idx_out[(size_t)(row0 + tid) * NQ + q] = (float)b;
    }
    __syncthreads();

    // ---- residual update (+ commit partial; LAST: quant = z - R') ----
    float ca = 0.f;
    const int rgrp = tid >> 3;
    const int lpos = tid & 7;
#pragma unroll
    for (int rr = 0; rr < 4; ++rr) {
        const int row = rr * 32 + rgrp;
        const float* rin  = Rin + (size_t)(row0 + row) * HDIM;
        const float* crow = cb + ((size_t)q * NCODE + idxbuf[row]) * HDIM;
        float* rout = Rout + (size_t)(row0 + row) * HDIM;
        const float* zr = LAST ? (zsrc + (size_t)(row0 + row) * HDIM) : nullptr;
#pragma unroll
        for (int j = 0; j < 16; ++j) {
            const int f4 = lpos + j * 8;
            float4 rv = *reinterpret_cast<const float4*>(rin + f4 * 4);
            float4 cv = *reinterpret_cast<const float4*>(crow + f4 * 4);
            float4 d;
            d.x = rv.x - cv.x; d.y = rv.y - cv.y;
            d.z = rv.z - cv.z; d.w = rv.w - cv.w;
            ca = fmaf(d.x, d.x, ca); ca = fmaf(d.y, d.y, ca);
            ca = fmaf(d.z, d.z, ca); ca = fmaf(d.w, d.w, ca);
            if constexpr (LAST) {
                float4 zv = *reinterpret_cast<const float4*>(zr + f4 * 4);
                float4 qv;
                qv.x = zv.x - d.x; qv.y = zv.y - d.y;
                qv.z = zv.z - d.z; qv.w = zv.w - d.w;
                *reinterpret_cast<float4*>(rout + f4 * 4) = qv;
            } else {
                *reinterpret_cast<float4*>(rout + f4 * 4) = d;
            }
        }
    }

    red[tid] = ca;
    __syncthreads();
    for (int s = 128; s > 0; s >>= 1) {
        if (tid < s) red[tid] += red[tid + s];
        __syncthreads();
    }
    if (tid == 0) commitP[q * 512 + blockIdx.x] = red[0];
}

// ---------------------------------------------------------------------------
// deterministic final loss reduction
// ---------------------------------------------------------------------------
__global__ __launch_bounds__(256)
void loss_reduce(const float* __restrict__ cP, int nc,
                 const float* __restrict__ rP, int nr,
                 float* __restrict__ out2)
{
    __shared__ float red[256];
    const int tid = threadIdx.x;

    float s = 0.f;
    for (int i = tid; i < nc; i += 256) s += cP[i];
    red[tid] = s;
    __syncthreads();
    for (int st = 128; st > 0; st >>= 1) {
        if (tid < st) red[tid] += red[tid + st];
        __syncthreads();
    }
    float ctot = red[0];
    __syncthreads();

    s = 0.f;
    for (int i = tid; i < nr; i += 256) s += rP[i];
    red[tid] = s;
    __syncthreads();
    for (int st = 128; st > 0; st >>= 1) {
        if (tid < st) red[tid] += red[tid + st];
        __syncthreads();
    }
    if (tid == 0) {
        out2[0] = red[0] / ((float)BATCH * (float)EDIM);
        out2[1] = 0.25f * ctot / ((float)BATCH * (float)HDIM);
    }
}

// ---------------------------------------------------------------------------
extern "C" void kernel_launch(void* const* d_in, const int* in_sizes, int n_in,
                              void* d_out, int out_size, void* d_ws, size_t ws_size,
                              hipStream_t stream)
{
    const float* x   = (const float*)d_in[0];
    const float* ew1 = (const float*)d_in[1];
    const float* eb1 = (const float*)d_in[2];
    const float* ew2 = (const float*)d_in[3];
    const float* eb2 = (const float*)d_in[4];
    const float* cb  = (const float*)d_in[5];
    const float* dw1 = (const float*)d_in[6];
    const float* db1 = (const float*)d_in[7];
    const float* dw2 = (const float*)d_in[8];
    const float* db2 = (const float*)d_in[9];

    float* out  = (float*)d_out;
    float* ws   = (float*)d_ws;
    float* bufA = ws + WS_BUFA;
    float* bufB = ws + WS_BUFB;
    unsigned short* cbs = (unsigned short*)(ws + WS_CBSPL);
    float* cn   = ws + WS_CNORM;
    float* cP   = ws + WS_COMMITP;
    float* rP   = ws + WS_RECONP;
    unsigned short* w1s = (unsigned short*)(ws + WS_W1S);
    unsigned short* w2s = (unsigned short*)(ws + WS_W2S);
    unsigned short* w3s = (unsigned short*)(ws + WS_W3S);
    unsigned short* w4s = (unsigned short*)(ws + WS_W4S);

    // one-shot prep: codebook norms + all f16 hi/lo splits
    cnorm_kernel<<<NQ * NCODE, 64, 0, stream>>>(cb, cn);
    split_cb<<<256, 256, 0, stream>>>(cb, cbs);
    split_w<<<(EDIM / 16) * 2 * HDIM / 256, 256, 0, stream>>>(ew1, w1s, HDIM, EDIM);
    split_w<<<(HDIM / 16) * 2 * HDIM / 256, 256, 0, stream>>>(ew2, w2s, HDIM, HDIM);
    split_w<<<(HDIM / 16) * 2 * HDIM / 256, 256, 0, stream>>>(dw1, w3s, HDIM, HDIM);
    split_w<<<(HDIM / 16) * 2 * EDIM / 256, 256, 0, stream>>>(dw2, w4s, EDIM, HDIM);

    // encoder (reg-only MFMA)
    gemm_reg<256, true, false><<<dim3(HDIM / 256, BATCH / 128), 256, 0, stream>>>(
        x, w1s, eb1, bufA, nullptr, nullptr, HDIM, EDIM);
    gemm_reg<256, false, false><<<dim3(HDIM / 256, BATCH / 128), 256, 0, stream>>>(
        bufA, w2s, eb2, bufB, nullptr, nullptr, HDIM, HDIM);

    // residual VQ: 4 MFMA stages
    float* idxo = out + OUT_IDX_OFF;
    vq_stage<false><<<512, 256, 0, stream>>>(0, bufB, bufA, nullptr, cbs, cb, cn, idxo, cP);
    vq_stage<false><<<512, 256, 0, stream>>>(1, bufA, bufA, nullptr, cbs, cb, cn, idxo, cP);
    vq_stage<false><<<512, 256, 0, stream>>>(2, bufA, bufA, nullptr, cbs, cb, cn, idxo, cP);
    vq_stage<true ><<<512, 256, 0, stream>>>(3, bufA, bufB, bufB,    cbs, cb, cn, idxo, cP);

    // decoder (reg-only MFMA)
    gemm_reg<256, true, false><<<dim3(HDIM / 256, BATCH / 128), 256, 0, stream>>>(
        bufB, w3s, db1, bufA, nullptr, nullptr, HDIM, HDIM);
    gemm_reg<128, false, true><<<dim3(EDIM / 128, BATCH / 128), 256, 0, stream>>>(
        bufA, w4s, db2, out, x, rP, EDIM, HDIM);

    // losses
    loss_reduce<<<1, 256, 0, stream>>>(cP, NQ * 512, rP,
                                       (BATCH / 128) * (EDIM / 128),
                                       out + OUT_RL_OFF);
}